// Round 8
// baseline (960.650 us; speedup 1.0000x reference)
//
#include <hip/hip_runtime.h>
#include <math.h>
#include <stdint.h>

// Problem constants (from reference)
#define NN   10000      // nodes
#define EE   160000     // edges
#define BB   32         // batch
#define FDIM 384        // K*(DIM_IN+DIM_OUT) = 3*128
#define EE_PAD (EE + 4 * NN)   // CSR rows padded to multiples of 4 edges
#define NB_FULL 1250    // full-spmm: 8 nodes / 256-thr block (32 lanes x f16x4 per node)
#define NB_HALF 625     // half-spmm: 16 nodes / 256-thr block (16 lanes x f16x4 per node)

typedef _Float16 f16x8 __attribute__((ext_vector_type(8)));
typedef _Float16 f16x4 __attribute__((ext_vector_type(4)));
typedef _Float16 f16x2 __attribute__((ext_vector_type(2)));
typedef __fp16   pk16  __attribute__((ext_vector_type(2)));   // builtin-native half2
typedef float    f32x4 __attribute__((ext_vector_type(4)));

// ---------------- CSR build (4-aligned padded rows) ----------------

__global__ void count_kernel(const int* __restrict__ ei, int* __restrict__ counts) {
    int e = blockIdx.x * blockDim.x + threadIdx.x;
    if (e < EE) atomicAdd(&counts[ei[e]], 1);
}

__global__ void scan_kernel(const int* __restrict__ counts, int* __restrict__ row_ptr) {
    __shared__ int sh[1024];
    int t = threadIdx.x;
    const int CH = 10;                       // 1024*10 >= NN
    int base = t * CH;
    int local[CH];
    int s = 0;
#pragma unroll
    for (int i = 0; i < CH; i++) {
        int idx = base + i;
        int v = (idx < NN) ? ((counts[idx] + 3) & ~3) : 0;   // pad row to x4
        local[i] = v; s += v;
    }
    sh[t] = s;
    __syncthreads();
    for (int off = 1; off < 1024; off <<= 1) {
        int add = (t >= off) ? sh[t - off] : 0;
        __syncthreads();
        sh[t] += add;
        __syncthreads();
    }
    int prefix = (t == 0) ? 0 : sh[t - 1];
#pragma unroll
    for (int i = 0; i < CH; i++) {
        int idx = base + i;
        if (idx < NN) row_ptr[idx] = prefix;
        prefix += local[i];
    }
    if (t == 1023) row_ptr[NN] = prefix;     // <= EE_PAD
}

// cols/weights for pad slots stay 0 (memset) -> gather row 0 with w=0: no-op.
__global__ void fill_kernel(const int* __restrict__ ei, const float* __restrict__ ew,
                            const int* __restrict__ row_ptr, int* __restrict__ cursor,
                            int* __restrict__ col_s, _Float16* __restrict__ w_h) {
    int e = blockIdx.x * blockDim.x + threadIdx.x;
    if (e < EE) {
        int r = ei[e];
        int c = ei[EE + e];
        int pos = row_ptr[r] + atomicAdd(&cursor[r], 1);
        col_s[pos] = c;
        w_h[pos] = (_Float16)ew[e];
    }
}

// ---------------- fp32 -> fp16 conversions (weights once; in/hx per chunk) ----------------

__global__ void wconv_kernel(const float* __restrict__ wg, const float* __restrict__ wc,
                             _Float16* __restrict__ whg, _Float16* __restrict__ whc) {
    int i = blockIdx.x * blockDim.x + threadIdx.x;
    if (i < 128 * FDIM) whg[i] = (_Float16)wg[i];
    if (i < 64 * FDIM)  whc[i] = (_Float16)wc[i];
}

__global__ void cvt_h_kernel(const float* __restrict__ a, const float* __restrict__ b,
                             _Float16* __restrict__ ah, _Float16* __restrict__ bh, int n4) {
    int i = blockIdx.x * blockDim.x + threadIdx.x;
    if (i >= n4) return;
    const float* s = (blockIdx.y == 0) ? a : b;
    _Float16*    d = (blockIdx.y == 0) ? ah : bh;
    float4 v = reinterpret_cast<const float4*>(s)[i];
    f16x4 h; h[0] = (_Float16)v.x; h[1] = (_Float16)v.y;
             h[2] = (_Float16)v.z; h[3] = (_Float16)v.w;
    reinterpret_cast<f16x4*>(d)[i] = h;
}

// ---------------- SpMM (CSR row-gather), f16 storage / fp32 accumulate ----------------
// XCD-aware block mapping: all blocks of batch b land on XCD (b&7); per-XCD
// sequential working set = one batch's f16 src rows (~2.5 MB) -> resident in
// that XCD's 4 MiB L2.
__device__ inline void sp_map(int NB, int bc_n, int& b, int& nb) {
    int L = blockIdx.x;
    if ((bc_n & 7) == 0) {                   // bijective when bc_n % 8 == 0
        int xcd = L & 7;
        int x   = L >> 3;
        b  = xcd + 8 * (x / NB);
        nb = x % NB;
    } else {
        b  = L / NB;
        nb = L % NB;
    }
}

// Inner gather: lane accumulates 4 feats over a 4-aligned edge span.
// Addressing: wave-uniform SGPR base + 32-bit voffset = (col<<sh) + fo_all.
// Main body = 16 edges (19 loads in flight for latency hiding); tails 8/4.
// Edge pairs packed via v_perm_b32 and reduced with v_dot2_f32_f16 (f32 acc).
__device__ __forceinline__ void gather_acc4(
        const int* __restrict__ col_s, const _Float16* __restrict__ w_h,
        const char* __restrict__ srcb, int sh, unsigned fo_all,
        int start, int end, float& a0, float& a1, float& a2, float& a3)
{
#if __has_builtin(__builtin_amdgcn_fdot2) && __has_builtin(__builtin_amdgcn_perm)
#define GDOT(da, db, wp)                                                              \
    a0 = __builtin_amdgcn_fdot2(__builtin_bit_cast(pk16,                              \
             __builtin_amdgcn_perm(db.x, da.x, 0x05040100u)), wp, a0, false);         \
    a1 = __builtin_amdgcn_fdot2(__builtin_bit_cast(pk16,                              \
             __builtin_amdgcn_perm(db.x, da.x, 0x07060302u)), wp, a1, false);         \
    a2 = __builtin_amdgcn_fdot2(__builtin_bit_cast(pk16,                              \
             __builtin_amdgcn_perm(db.y, da.y, 0x05040100u)), wp, a2, false);         \
    a3 = __builtin_amdgcn_fdot2(__builtin_bit_cast(pk16,                              \
             __builtin_amdgcn_perm(db.y, da.y, 0x07060302u)), wp, a3, false);
#define GLD(c) *reinterpret_cast<const uint2*>(srcb + (((unsigned)(c) << sh) + fo_all))
    int j = start;
    for (; j + 16 <= end; j += 16) {         // 16 gathers + 8 meta in flight
        int4  ca = *reinterpret_cast<const int4*>(&col_s[j]);
        int4  cb = *reinterpret_cast<const int4*>(&col_s[j + 4]);
        int4  cc = *reinterpret_cast<const int4*>(&col_s[j + 8]);
        int4  cd = *reinterpret_cast<const int4*>(&col_s[j + 12]);
        uint2 wv0 = *reinterpret_cast<const uint2*>(&w_h[j]);
        uint2 wv1 = *reinterpret_cast<const uint2*>(&w_h[j + 4]);
        uint2 wv2 = *reinterpret_cast<const uint2*>(&w_h[j + 8]);
        uint2 wv3 = *reinterpret_cast<const uint2*>(&w_h[j + 12]);
        uint2 d0 = GLD(ca.x), d1 = GLD(ca.y), d2 = GLD(ca.z), d3 = GLD(ca.w);
        uint2 d4 = GLD(cb.x), d5 = GLD(cb.y), d6 = GLD(cb.z), d7 = GLD(cb.w);
        uint2 d8 = GLD(cc.x), d9 = GLD(cc.y), da_ = GLD(cc.z), db_ = GLD(cc.w);
        uint2 dc_ = GLD(cd.x), dd_ = GLD(cd.y), de_ = GLD(cd.z), df_ = GLD(cd.w);
        GDOT(d0, d1, __builtin_bit_cast(pk16, wv0.x))
        GDOT(d2, d3, __builtin_bit_cast(pk16, wv0.y))
        GDOT(d4, d5, __builtin_bit_cast(pk16, wv1.x))
        GDOT(d6, d7, __builtin_bit_cast(pk16, wv1.y))
        GDOT(d8, d9, __builtin_bit_cast(pk16, wv2.x))
        GDOT(da_, db_, __builtin_bit_cast(pk16, wv2.y))
        GDOT(dc_, dd_, __builtin_bit_cast(pk16, wv3.x))
        GDOT(de_, df_, __builtin_bit_cast(pk16, wv3.y))
    }
    if (j + 8 <= end) {
        int4  ca = *reinterpret_cast<const int4*>(&col_s[j]);
        int4  cb = *reinterpret_cast<const int4*>(&col_s[j + 4]);
        uint2 wv0 = *reinterpret_cast<const uint2*>(&w_h[j]);
        uint2 wv1 = *reinterpret_cast<const uint2*>(&w_h[j + 4]);
        uint2 d0 = GLD(ca.x), d1 = GLD(ca.y), d2 = GLD(ca.z), d3 = GLD(ca.w);
        uint2 d4 = GLD(cb.x), d5 = GLD(cb.y), d6 = GLD(cb.z), d7 = GLD(cb.w);
        GDOT(d0, d1, __builtin_bit_cast(pk16, wv0.x))
        GDOT(d2, d3, __builtin_bit_cast(pk16, wv0.y))
        GDOT(d4, d5, __builtin_bit_cast(pk16, wv1.x))
        GDOT(d6, d7, __builtin_bit_cast(pk16, wv1.y))
        j += 8;
    }
    if (j < end) {                           // exactly 4 (rows padded to x4)
        int4  ca = *reinterpret_cast<const int4*>(&col_s[j]);
        uint2 wv0 = *reinterpret_cast<const uint2*>(&w_h[j]);
        uint2 d0 = GLD(ca.x), d1 = GLD(ca.y), d2 = GLD(ca.z), d3 = GLD(ca.w);
        GDOT(d0, d1, __builtin_bit_cast(pk16, wv0.x))
        GDOT(d2, d3, __builtin_bit_cast(pk16, wv0.y))
    }
#undef GLD
#undef GDOT
#else
    for (int j = start; j < end; ++j) {
        int c = col_s[j]; float w = (float)w_h[j];
        f16x4 v = *reinterpret_cast<const f16x4*>(srcb + (((unsigned)c << sh) + fo_all));
        a0 += w * (float)v[0]; a1 += w * (float)v[1];
        a2 += w * (float)v[2]; a3 += w * (float)v[3];
    }
#endif
}

// Full-width (128 feat f16): 32 lanes per node, lane -> f16x4.
// Segments A/B always share stride (sh); B is at byte delta deltaB from base.
__global__ __launch_bounds__(256)
void spmm_full16(const int* __restrict__ row_ptr, const int* __restrict__ col_s,
                 const _Float16* __restrict__ w_h,
                 const _Float16* __restrict__ srcBase, int sh, int deltaB,
                 const _Float16* __restrict__ subA, const _Float16* __restrict__ subB,
                 float alpha, _Float16* __restrict__ outbuf, int bc_n) {
    int b, nb; sp_map(NB_FULL, bc_n, b, nb);
    int node = nb * 8 + (threadIdx.x >> 5);
    int g    = threadIdx.x & 31;             // 32 lanes x 4 feats = 128
    int fo, db;
    if (g < 16) { fo = g * 4;        db = 0;      }
    else        { fo = (g - 16) * 4; db = deltaB; }
    unsigned fo_all = ((unsigned)(b * NN) << sh) + (unsigned)db + (unsigned)(fo * 2);
    int start = row_ptr[node], end = row_ptr[node + 1];
    long base = (long)b * NN;
    float a0 = 0.f, a1 = 0.f, a2 = 0.f, a3 = 0.f;
    gather_acc4(col_s, w_h, (const char*)srcBase, sh, fo_all, start, end, a0, a1, a2, a3);
    a0 *= alpha; a1 *= alpha; a2 *= alpha; a3 *= alpha;
    if (subA) {
        const _Float16* sub = (g < 16) ? subA : subB;
        f16x4 s = *reinterpret_cast<const f16x4*>(&sub[(base + node) * 64 + fo]);
        a0 -= (float)s[0]; a1 -= (float)s[1]; a2 -= (float)s[2]; a3 -= (float)s[3];
    }
    f16x4 r; r[0] = (_Float16)a0; r[1] = (_Float16)a1;
             r[2] = (_Float16)a2; r[3] = (_Float16)a3;
    *reinterpret_cast<f16x4*>(&outbuf[(base + node) * 128 + g * 4]) = r;
}

// Half-width (64 feat f16): 16 lanes per node, lane -> f16x4.
// Writes outbuf[(b*NN+node)*128 + fo]; caller pre-offsets outbuf by +64.
__global__ __launch_bounds__(256)
void spmm_half16(const int* __restrict__ row_ptr, const int* __restrict__ col_s,
                 const _Float16* __restrict__ w_h,
                 const _Float16* __restrict__ src, int sh,
                 const _Float16* __restrict__ sub, float alpha,
                 _Float16* __restrict__ outbuf, int bc_n) {
    int b, nb; sp_map(NB_HALF, bc_n, b, nb);
    int node = nb * 16 + (threadIdx.x >> 4);
    int fo   = (threadIdx.x & 15) * 4;       // 16 lanes x 4 feats = 64
    unsigned fo_all = ((unsigned)(b * NN) << sh) + (unsigned)(fo * 2);
    int start = row_ptr[node], end = row_ptr[node + 1];
    long base = (long)b * NN;
    float a0 = 0.f, a1 = 0.f, a2 = 0.f, a3 = 0.f;
    gather_acc4(col_s, w_h, (const char*)src, sh, fo_all, start, end, a0, a1, a2, a3);
    a0 *= alpha; a1 *= alpha; a2 *= alpha; a3 *= alpha;
    if (sub) {
        f16x4 s = *reinterpret_cast<const f16x4*>(&sub[(base + node) * 64 + fo]);
        a0 -= (float)s[0]; a1 -= (float)s[1]; a2 -= (float)s[2]; a3 -= (float)s[3];
    }
    f16x4 r; r[0] = (_Float16)a0; r[1] = (_Float16)a1;
             r[2] = (_Float16)a2; r[3] = (_Float16)a3;
    *reinterpret_cast<f16x4*>(&outbuf[(base + node) * 128 + fo]) = r;
}

// ---------------- MFMA GEMM over virtual x_diff = [x0 | W1 | W2], all-f16 ----------------
// MODE 0: NOUT=128 gates -> z (f16), rh = sigmoid(r)*hx (f16)
// MODE 1: NOUT=64 candidate -> out = (1-z)*hx + z*tanh(cand) (fp32)
template <int MODE>
__global__ __launch_bounds__(256)
void gemm_mfma(const _Float16* __restrict__ in_h,
               const _Float16* __restrict__ hxl_h,  // hx_h (pass A) or rh (pass B)
               const _Float16* __restrict__ W1h,
               const _Float16* __restrict__ W2h,
               const _Float16* __restrict__ Wh,     // (NOUT, 384) row-major f16
               const float* __restrict__ bias,      // (NOUT)
               const float* __restrict__ hx32,      // true hx, fp32
               const _Float16* __restrict__ zbuf,   // MODE1: read z
               float* __restrict__ outf,            // MODE1: final out (fp32)
               _Float16* __restrict__ z_o,          // MODE0: z
               _Float16* __restrict__ rh_o,         // MODE0: rh
               int Mchunk)
{
    const int NOUT = (MODE == 0) ? 128 : 64;
    const int TNF  = NOUT / 16;              // # of 16-col MFMA fragments
    const int PIT  = 40;                     // LDS pitch in halfs (80 B)

    __shared__ _Float16 Alds[64 * PIT];
    __shared__ _Float16 Blds[NOUT * PIT];

    int tid  = threadIdx.x;
    int lane = tid & 63;
    int w    = tid >> 6;                     // wave 0..3
    int lr   = lane & 15;                    // row (A) / col (B,D) within 16
    int lko  = (lane >> 4) * 8;              // k offset within 32

    long mbase = (long)blockIdx.x * 64;

    f32x4 acc[TNF];
#pragma unroll
    for (int f = 0; f < TNF; f++) acc[f] = (f32x4){0.f, 0.f, 0.f, 0.f};

    for (int k0 = 0; k0 < FDIM; k0 += 32) {
        // segment select (wave-uniform; boundaries 64/128/256 are 32-aligned)
        const _Float16* src; int stride; int koff;
        if      (k0 < 64)  { src = in_h;  stride = 64;  koff = 0;   }
        else if (k0 < 128) { src = hxl_h; stride = 64;  koff = 64;  }
        else if (k0 < 256) { src = W1h;   stride = 128; koff = 128; }
        else               { src = W2h;   stride = 128; koff = 256; }

        // A tile: 64 rows x 32 k halfs.  4 threads/row, one 16B load each.
        {
            int rr = tid >> 2;
            int q  = tid & 3;
            long row = mbase + rr;
            if (row >= Mchunk) row = Mchunk - 1;
            *reinterpret_cast<f16x8*>(&Alds[rr * PIT + q * 8]) =
                *reinterpret_cast<const f16x8*>(&src[row * (long)stride + (k0 - koff) + q * 8]);
        }
        // B tile: NOUT x 32 halfs from pre-converted weights.
        {
            for (int l = tid * 8; l < NOUT * 32; l += 256 * 8) {
                int n  = l >> 5;
                int kk = l & 31;             // 0,8,16,24
                *reinterpret_cast<f16x8*>(&Blds[n * PIT + kk]) =
                    *reinterpret_cast<const f16x8*>(&Wh[n * FDIM + k0 + kk]);
            }
        }
        __syncthreads();

        f16x8 a = *reinterpret_cast<const f16x8*>(&Alds[(w * 16 + lr) * PIT + lko]);
#pragma unroll
        for (int f = 0; f < TNF; f++) {
            f16x8 bfr = *reinterpret_cast<const f16x8*>(&Blds[(lr + 16 * f) * PIT + lko]);
            acc[f] = __builtin_amdgcn_mfma_f32_16x16x32_f16(a, bfr, acc[f], 0, 0, 0);
        }
        __syncthreads();
    }

    // epilogue: D layout col = lane&15, row = (lane>>4)*4 + reg   [m89]
#pragma unroll
    for (int f = 0; f < TNF; f++) {
        int g = lr + 16 * f;
#pragma unroll
        for (int j = 0; j < 4; j++) {
            long m = mbase + w * 16 + (lane >> 4) * 4 + j;
            if (m >= Mchunk) continue;
            float v = acc[f][j] + bias[g];
            if (MODE == 0) {
                float s = 1.f / (1.f + __expf(-v));
                if (g < 64) z_o[m * 64 + g] = (_Float16)s;
                else        rh_o[m * 64 + (g - 64)] = (_Float16)(s * hx32[m * 64 + (g - 64)]);
            } else {
                float cnd = tanhf(v);
                float zz = (float)zbuf[m * 64 + g];
                outf[m * 64 + g] = (1.f - zz) * hx32[m * 64 + g] + zz * cnd;
            }
        }
    }
}

// ---------------- launch ----------------

extern "C" void kernel_launch(void* const* d_in, const int* in_sizes, int n_in,
                              void* d_out, int out_size, void* d_ws, size_t ws_size,
                              hipStream_t stream) {
    const float* inputs = (const float*)d_in[0];
    const float* hx     = (const float*)d_in[1];
    const int*   ei     = (const int*)d_in[2];
    const float* ew     = (const float*)d_in[3];
    const float* wg     = (const float*)d_in[4];
    const float* wc     = (const float*)d_in[5];
    const float* bg     = (const float*)d_in[6];
    const float* bc     = (const float*)d_in[7];
    float* out = (float*)d_out;

    // CSR + f16-weight footprint
    const size_t csr_bytes = (size_t)(NN + 1) * 4 + (size_t)NN * 4 * 2
                           + (size_t)EE_PAD * 6
                           + (size_t)(128 + 64) * FDIM * 2 + 512;
    // per-batch f16 intermediates: in_h,hx_h,rh,z (64 each) + W1h,W2h (128 each)
    const size_t per_batch = (size_t)NN * 512 * 2;   // 10.24 MB

    int bc_n = 1;
    const int cand[6] = {32, 16, 8, 4, 2, 1};
    for (int i = 0; i < 6; i++) {
        if (csr_bytes + (size_t)cand[i] * per_batch <= ws_size) { bc_n = cand[i]; break; }
    }

    // workspace layout (chunk-local, all f16 multiples of 16B)
    uint8_t* p = (uint8_t*)d_ws;
    _Float16* W1h  = (_Float16*)p; p += (size_t)bc_n * NN * 128 * 2;
    _Float16* W2h  = (_Float16*)p; p += (size_t)bc_n * NN * 128 * 2;
    _Float16* in_h = (_Float16*)p; p += (size_t)bc_n * NN * 64 * 2;
    _Float16* hx_h = (_Float16*)p; p += (size_t)bc_n * NN * 64 * 2;
    _Float16* rh   = (_Float16*)p; p += (size_t)bc_n * NN * 64 * 2;
    _Float16* zh   = (_Float16*)p; p += (size_t)bc_n * NN * 64 * 2;
    int* row_ptr = (int*)p;  p += (size_t)(NN + 1) * 4;
    p = (uint8_t*)(((uintptr_t)p + 15) & ~(uintptr_t)15);
    int* counts  = (int*)p;  p += (size_t)NN * 4;
    int* cursor  = (int*)p;  p += (size_t)NN * 4;            // counts,cursor,col,w contiguous
    int* col_s   = (int*)p;  p += (size_t)EE_PAD * 4;        // 16B-aligned (NN*8 mult of 16)
    _Float16* w_h = (_Float16*)p; p += (size_t)EE_PAD * 2;   // 8B-aligned accesses only
    p = (uint8_t*)(((uintptr_t)p + 63) & ~(uintptr_t)63);
    _Float16* whg = (_Float16*)p; p += (size_t)128 * FDIM * 2;
    _Float16* whc = (_Float16*)p;

    // CSR build (inputs re-restored every call -> rebuild every call).
    // One memset covers counts+cursor+col_s+w_h (pads must be col=0,w=0).
    hipMemsetAsync(counts, 0, (size_t)NN * 8 + (size_t)EE_PAD * 6, stream);
    count_kernel<<<(EE + 255) / 256, 256, 0, stream>>>(ei, counts);
    scan_kernel<<<1, 1024, 0, stream>>>(counts, row_ptr);
    fill_kernel<<<(EE + 255) / 256, 256, 0, stream>>>(ei, ew, row_ptr, cursor, col_s, w_h);
    wconv_kernel<<<(128 * FDIM + 255) / 256, 256, 0, stream>>>(wg, wc, whg, whc);

    for (int b0 = 0; b0 < BB; b0 += bc_n) {
        const float* in_c = inputs + (size_t)b0 * NN * 64;
        const float* hx_c = hx     + (size_t)b0 * NN * 64;
        float*       out_c = out   + (size_t)b0 * NN * 64;
        int Mchunk = bc_n * NN;
        int gemm_blocks = (Mchunk + 63) / 64;
        int n4 = bc_n * NN * 64 / 4;

        // f16 copies of this chunk's inputs/hx
        dim3 cg((n4 + 255) / 256, 2);
        cvt_h_kernel<<<cg, 256, 0, stream>>>(in_c, hx_c, in_h, hx_h, n4);

        int deltaA = (int)((const char*)hx_h - (const char*)in_h);

        // Pass A: x0 = [inputs|hx]  (both segments stride 64 f16 -> sh=7)
        spmm_full16<<<NB_FULL * bc_n, 256, 0, stream>>>(row_ptr, col_s, w_h,
                                                        in_h, 7, deltaA,
                                                        nullptr, nullptr, 1.f, W1h, bc_n);
        // W2 = 2*conv(W1) - x0  (W1 unified [row][128] -> sh=8, deltaB=128B)
        spmm_full16<<<NB_FULL * bc_n, 256, 0, stream>>>(row_ptr, col_s, w_h,
                                                        W1h, 8, 128,
                                                        in_h, hx_h, 2.f, W2h, bc_n);
        gemm_mfma<0><<<gemm_blocks, 256, 0, stream>>>(in_h, hx_h, W1h, W2h, whg, bg,
                                                      hx_c, nullptr, nullptr, zh, rh, Mchunk);
        // Pass B: x0' = [inputs|r*hx]; inputs-half of W1h/W2h reused from pass A
        spmm_half16<<<NB_HALF * bc_n, 256, 0, stream>>>(row_ptr, col_s, w_h, rh, 7,
                                                        nullptr, 1.f, W1h + 64, bc_n);
        spmm_half16<<<NB_HALF * bc_n, 256, 0, stream>>>(row_ptr, col_s, w_h, W1h + 64, 8,
                                                        rh, 2.f, W2h + 64, bc_n);
        gemm_mfma<1><<<gemm_blocks, 256, 0, stream>>>(in_h, rh, W1h, W2h, whc, bc,
                                                      hx_c, zh, out_c, nullptr, nullptr, Mchunk);
    }
}

// Round 9
// 910.738 us; speedup vs baseline: 1.0548x; 1.0548x over previous
//
#include <hip/hip_runtime.h>
#include <math.h>
#include <stdint.h>

// Problem constants (from reference)
#define NN   10000      // nodes
#define EE   160000     // edges
#define BB   32         // batch
#define FDIM 384        // K*(DIM_IN+DIM_OUT) = 3*128
#define EE_PAD (EE + 4 * NN)   // CSR rows padded to multiples of 4 edges
#define NB_FULL 1250    // full-spmm: 8 nodes / 256-thr block (32 lanes x f16x4 per node)
#define NB_HALF 625     // half-spmm: 16 nodes / 256-thr block (16 lanes x f16x4 per node)

typedef _Float16 f16x8 __attribute__((ext_vector_type(8)));
typedef _Float16 f16x4 __attribute__((ext_vector_type(4)));
typedef _Float16 f16x2 __attribute__((ext_vector_type(2)));
typedef __fp16   pk16  __attribute__((ext_vector_type(2)));   // builtin-native half2
typedef float    f32x4 __attribute__((ext_vector_type(4)));

// ---------------- CSR build (4-aligned padded rows) ----------------

__global__ void count_kernel(const int* __restrict__ ei, int* __restrict__ counts) {
    int e = blockIdx.x * blockDim.x + threadIdx.x;
    if (e < EE) atomicAdd(&counts[ei[e]], 1);
}

__global__ void scan_kernel(const int* __restrict__ counts, int* __restrict__ row_ptr) {
    __shared__ int sh[1024];
    int t = threadIdx.x;
    const int CH = 10;                       // 1024*10 >= NN
    int base = t * CH;
    int local[CH];
    int s = 0;
#pragma unroll
    for (int i = 0; i < CH; i++) {
        int idx = base + i;
        int v = (idx < NN) ? ((counts[idx] + 3) & ~3) : 0;   // pad row to x4
        local[i] = v; s += v;
    }
    sh[t] = s;
    __syncthreads();
    for (int off = 1; off < 1024; off <<= 1) {
        int add = (t >= off) ? sh[t - off] : 0;
        __syncthreads();
        sh[t] += add;
        __syncthreads();
    }
    int prefix = (t == 0) ? 0 : sh[t - 1];
#pragma unroll
    for (int i = 0; i < CH; i++) {
        int idx = base + i;
        if (idx < NN) row_ptr[idx] = prefix;
        prefix += local[i];
    }
    if (t == 1023) row_ptr[NN] = prefix;     // <= EE_PAD
}

// cols/weights for pad slots stay 0 (memset) -> gather row 0 with w=0: no-op.
__global__ void fill_kernel(const int* __restrict__ ei, const float* __restrict__ ew,
                            const int* __restrict__ row_ptr, int* __restrict__ cursor,
                            int* __restrict__ col_s, _Float16* __restrict__ w_h) {
    int e = blockIdx.x * blockDim.x + threadIdx.x;
    if (e < EE) {
        int r = ei[e];
        int c = ei[EE + e];
        int pos = row_ptr[r] + atomicAdd(&cursor[r], 1);
        col_s[pos] = c;
        w_h[pos] = (_Float16)ew[e];
    }
}

// ---------------- fp32 -> fp16 conversions (weights once; in/hx per chunk) ----------------

__global__ void wconv_kernel(const float* __restrict__ wg, const float* __restrict__ wc,
                             _Float16* __restrict__ whg, _Float16* __restrict__ whc) {
    int i = blockIdx.x * blockDim.x + threadIdx.x;
    if (i < 128 * FDIM) whg[i] = (_Float16)wg[i];
    if (i < 64 * FDIM)  whc[i] = (_Float16)wc[i];
}

__global__ void cvt_h_kernel(const float* __restrict__ a, const float* __restrict__ b,
                             _Float16* __restrict__ ah, _Float16* __restrict__ bh, int n4) {
    int i = blockIdx.x * blockDim.x + threadIdx.x;
    if (i >= n4) return;
    const float* s = (blockIdx.y == 0) ? a : b;
    _Float16*    d = (blockIdx.y == 0) ? ah : bh;
    float4 v = reinterpret_cast<const float4*>(s)[i];
    f16x4 h; h[0] = (_Float16)v.x; h[1] = (_Float16)v.y;
             h[2] = (_Float16)v.z; h[3] = (_Float16)v.w;
    reinterpret_cast<f16x4*>(d)[i] = h;
}

// ---------------- SpMM (CSR row-gather), f16 storage / fp32 accumulate ----------------
// XCD-aware block mapping: all blocks of batch b land on XCD (b&7); per-XCD
// sequential working set = one batch's f16 src rows (~2.5 MB) -> resident in
// that XCD's 4 MiB L2.  NOTE (r5-r8): gather line delivery is pinned at
// ~1 TB/s/XCD (~25% of sequential L2) across all inner-loop shapes -> the
// random-line rate is a HW ceiling; only phantom-edge count is a knob.
__device__ inline void sp_map(int NB, int bc_n, int& b, int& nb) {
    int L = blockIdx.x;
    if ((bc_n & 7) == 0) {                   // bijective when bc_n % 8 == 0
        int xcd = L & 7;
        int x   = L >> 3;
        b  = xcd + 8 * (x / NB);
        nb = x % NB;
    } else {
        b  = L / NB;
        nb = L % NB;
    }
}

// Inner gather: lane accumulates 4 feats over a 4-aligned edge span.
// Addressing: wave-uniform SGPR base + 32-bit voffset = (col<<sh) + fo_all.
// 8-edge main body (round-6 schedule, VGPR ~24) + single 4-edge tail.
__device__ __forceinline__ void gather_acc4(
        const int* __restrict__ col_s, const _Float16* __restrict__ w_h,
        const char* __restrict__ srcb, int sh, unsigned fo_all,
        int start, int end, float& a0, float& a1, float& a2, float& a3)
{
#if __has_builtin(__builtin_amdgcn_fdot2) && __has_builtin(__builtin_amdgcn_perm)
#define GDOT(da, db, wp)                                                              \
    a0 = __builtin_amdgcn_fdot2(__builtin_bit_cast(pk16,                              \
             __builtin_amdgcn_perm(db.x, da.x, 0x05040100u)), wp, a0, false);         \
    a1 = __builtin_amdgcn_fdot2(__builtin_bit_cast(pk16,                              \
             __builtin_amdgcn_perm(db.x, da.x, 0x07060302u)), wp, a1, false);         \
    a2 = __builtin_amdgcn_fdot2(__builtin_bit_cast(pk16,                              \
             __builtin_amdgcn_perm(db.y, da.y, 0x05040100u)), wp, a2, false);         \
    a3 = __builtin_amdgcn_fdot2(__builtin_bit_cast(pk16,                              \
             __builtin_amdgcn_perm(db.y, da.y, 0x07060302u)), wp, a3, false);
#define GLD(c) *reinterpret_cast<const uint2*>(srcb + (((unsigned)(c) << sh) + fo_all))
    int j = start;
    for (; j + 8 <= end; j += 8) {           // 8 gathers + meta in flight
        int4  ca = *reinterpret_cast<const int4*>(&col_s[j]);
        int4  cb = *reinterpret_cast<const int4*>(&col_s[j + 4]);
        uint2 wv0 = *reinterpret_cast<const uint2*>(&w_h[j]);
        uint2 wv1 = *reinterpret_cast<const uint2*>(&w_h[j + 4]);
        uint2 d0 = GLD(ca.x), d1 = GLD(ca.y), d2 = GLD(ca.z), d3 = GLD(ca.w);
        uint2 d4 = GLD(cb.x), d5 = GLD(cb.y), d6 = GLD(cb.z), d7 = GLD(cb.w);
        GDOT(d0, d1, __builtin_bit_cast(pk16, wv0.x))
        GDOT(d2, d3, __builtin_bit_cast(pk16, wv0.y))
        GDOT(d4, d5, __builtin_bit_cast(pk16, wv1.x))
        GDOT(d6, d7, __builtin_bit_cast(pk16, wv1.y))
    }
    if (j < end) {                           // exactly 4 (rows padded to x4)
        int4  ca = *reinterpret_cast<const int4*>(&col_s[j]);
        uint2 wv0 = *reinterpret_cast<const uint2*>(&w_h[j]);
        uint2 d0 = GLD(ca.x), d1 = GLD(ca.y), d2 = GLD(ca.z), d3 = GLD(ca.w);
        GDOT(d0, d1, __builtin_bit_cast(pk16, wv0.x))
        GDOT(d2, d3, __builtin_bit_cast(pk16, wv0.y))
    }
#undef GLD
#undef GDOT
#else
    for (int j = start; j < end; ++j) {
        int c = col_s[j]; float w = (float)w_h[j];
        f16x4 v = *reinterpret_cast<const f16x4*>(srcb + (((unsigned)c << sh) + fo_all));
        a0 += w * (float)v[0]; a1 += w * (float)v[1];
        a2 += w * (float)v[2]; a3 += w * (float)v[3];
    }
#endif
}

// Full-width (128 feat f16): 32 lanes per node, lane -> f16x4.
// Segments A/B always share stride (sh); B is at byte delta deltaB from base.
__global__ __launch_bounds__(256)
void spmm_full16(const int* __restrict__ row_ptr, const int* __restrict__ col_s,
                 const _Float16* __restrict__ w_h,
                 const _Float16* __restrict__ srcBase, int sh, int deltaB,
                 const _Float16* __restrict__ subA, const _Float16* __restrict__ subB,
                 float alpha, _Float16* __restrict__ outbuf, int bc_n) {
    int b, nb; sp_map(NB_FULL, bc_n, b, nb);
    int node = nb * 8 + (threadIdx.x >> 5);
    int g    = threadIdx.x & 31;             // 32 lanes x 4 feats = 128
    int fo, db;
    if (g < 16) { fo = g * 4;        db = 0;      }
    else        { fo = (g - 16) * 4; db = deltaB; }
    unsigned fo_all = ((unsigned)(b * NN) << sh) + (unsigned)db + (unsigned)(fo * 2);
    int start = row_ptr[node], end = row_ptr[node + 1];
    long base = (long)b * NN;
    float a0 = 0.f, a1 = 0.f, a2 = 0.f, a3 = 0.f;
    gather_acc4(col_s, w_h, (const char*)srcBase, sh, fo_all, start, end, a0, a1, a2, a3);
    a0 *= alpha; a1 *= alpha; a2 *= alpha; a3 *= alpha;
    if (subA) {
        const _Float16* sub = (g < 16) ? subA : subB;
        f16x4 s = *reinterpret_cast<const f16x4*>(&sub[(base + node) * 64 + fo]);
        a0 -= (float)s[0]; a1 -= (float)s[1]; a2 -= (float)s[2]; a3 -= (float)s[3];
    }
    f16x4 r; r[0] = (_Float16)a0; r[1] = (_Float16)a1;
             r[2] = (_Float16)a2; r[3] = (_Float16)a3;
    *reinterpret_cast<f16x4*>(&outbuf[(base + node) * 128 + g * 4]) = r;
}

// Half-width (64 feat f16): 16 lanes per node, lane -> f16x4.
// Writes outbuf[(b*NN+node)*128 + fo]; caller pre-offsets outbuf by +64.
__global__ __launch_bounds__(256)
void spmm_half16(const int* __restrict__ row_ptr, const int* __restrict__ col_s,
                 const _Float16* __restrict__ w_h,
                 const _Float16* __restrict__ src, int sh,
                 const _Float16* __restrict__ sub, float alpha,
                 _Float16* __restrict__ outbuf, int bc_n) {
    int b, nb; sp_map(NB_HALF, bc_n, b, nb);
    int node = nb * 16 + (threadIdx.x >> 4);
    int fo   = (threadIdx.x & 15) * 4;       // 16 lanes x 4 feats = 64
    unsigned fo_all = ((unsigned)(b * NN) << sh) + (unsigned)(fo * 2);
    int start = row_ptr[node], end = row_ptr[node + 1];
    long base = (long)b * NN;
    float a0 = 0.f, a1 = 0.f, a2 = 0.f, a3 = 0.f;
    gather_acc4(col_s, w_h, (const char*)src, sh, fo_all, start, end, a0, a1, a2, a3);
    a0 *= alpha; a1 *= alpha; a2 *= alpha; a3 *= alpha;
    if (sub) {
        f16x4 s = *reinterpret_cast<const f16x4*>(&sub[(base + node) * 64 + fo]);
        a0 -= (float)s[0]; a1 -= (float)s[1]; a2 -= (float)s[2]; a3 -= (float)s[3];
    }
    f16x4 r; r[0] = (_Float16)a0; r[1] = (_Float16)a1;
             r[2] = (_Float16)a2; r[3] = (_Float16)a3;
    *reinterpret_cast<f16x4*>(&outbuf[(base + node) * 128 + fo]) = r;
}

// ---------------- MFMA GEMM over virtual x_diff = [x0 | W1 | W2], all-f16 ----------------
// BM=128 rows / 512 threads / 8 waves: halves barriers-per-row and per-block
// B staging vs BM=64.  Wave w owns rows [16w,16w+16).
// MODE 0: NOUT=128 gates -> z (f16), rh = sigmoid(r)*hx (f16)
// MODE 1: NOUT=64 candidate -> out = (1-z)*hx + z*tanh(cand) (fp32)
template <int MODE>
__global__ __launch_bounds__(512)
void gemm_mfma(const _Float16* __restrict__ in_h,
               const _Float16* __restrict__ hxl_h,  // hx_h (pass A) or rh (pass B)
               const _Float16* __restrict__ W1h,
               const _Float16* __restrict__ W2h,
               const _Float16* __restrict__ Wh,     // (NOUT, 384) row-major f16
               const float* __restrict__ bias,      // (NOUT)
               const float* __restrict__ hx32,      // true hx, fp32
               const _Float16* __restrict__ zbuf,   // MODE1: read z
               float* __restrict__ outf,            // MODE1: final out (fp32)
               _Float16* __restrict__ z_o,          // MODE0: z
               _Float16* __restrict__ rh_o,         // MODE0: rh
               int Mchunk)
{
    const int NOUT = (MODE == 0) ? 128 : 64;
    const int TNF  = NOUT / 16;              // # of 16-col MFMA fragments
    const int PIT  = 40;                     // LDS pitch in halfs (80 B)
    const int BM   = 128;

    __shared__ _Float16 Alds[BM * PIT];
    __shared__ _Float16 Blds[NOUT * PIT];

    int tid  = threadIdx.x;
    int lane = tid & 63;
    int w    = tid >> 6;                     // wave 0..7
    int lr   = lane & 15;                    // row (A) / col (B,D) within 16
    int lko  = (lane >> 4) * 8;              // k offset within 32

    long mbase = (long)blockIdx.x * BM;

    f32x4 acc[TNF];
#pragma unroll
    for (int f = 0; f < TNF; f++) acc[f] = (f32x4){0.f, 0.f, 0.f, 0.f};

    for (int k0 = 0; k0 < FDIM; k0 += 32) {
        // segment select (wave-uniform; boundaries 64/128/256 are 32-aligned)
        const _Float16* src; int stride; int koff;
        if      (k0 < 64)  { src = in_h;  stride = 64;  koff = 0;   }
        else if (k0 < 128) { src = hxl_h; stride = 64;  koff = 64;  }
        else if (k0 < 256) { src = W1h;   stride = 128; koff = 128; }
        else               { src = W2h;   stride = 128; koff = 256; }

        // A tile: 128 rows x 32 k halfs.  4 threads/row, one 16B load each.
        {
            int rr = tid >> 2;               // 0..127
            int q  = tid & 3;
            long row = mbase + rr;
            if (row >= Mchunk) row = Mchunk - 1;
            *reinterpret_cast<f16x8*>(&Alds[rr * PIT + q * 8]) =
                *reinterpret_cast<const f16x8*>(&src[row * (long)stride + (k0 - koff) + q * 8]);
        }
        // B tile: NOUT x 32 halfs from pre-converted weights.
        {
            int l = tid * 8;
            if (l < NOUT * 32) {             // MODE0: all 512 thr; MODE1: half
                int n  = l >> 5;
                int kk = l & 31;             // 0,8,16,24
                *reinterpret_cast<f16x8*>(&Blds[n * PIT + kk]) =
                    *reinterpret_cast<const f16x8*>(&Wh[n * FDIM + k0 + kk]);
            }
        }
        __syncthreads();

        f16x8 a = *reinterpret_cast<const f16x8*>(&Alds[(w * 16 + lr) * PIT + lko]);
#pragma unroll
        for (int f = 0; f < TNF; f++) {
            f16x8 bfr = *reinterpret_cast<const f16x8*>(&Blds[(lr + 16 * f) * PIT + lko]);
            acc[f] = __builtin_amdgcn_mfma_f32_16x16x32_f16(a, bfr, acc[f], 0, 0, 0);
        }
        __syncthreads();
    }

    // epilogue: D layout col = lane&15, row = (lane>>4)*4 + reg   [m89]
#pragma unroll
    for (int f = 0; f < TNF; f++) {
        int g = lr + 16 * f;
#pragma unroll
        for (int j = 0; j < 4; j++) {
            long m = mbase + w * 16 + (lane >> 4) * 4 + j;
            if (m >= Mchunk) continue;
            float v = acc[f][j] + bias[g];
            if (MODE == 0) {
                float s = 1.f / (1.f + __expf(-v));
                if (g < 64) z_o[m * 64 + g] = (_Float16)s;
                else        rh_o[m * 64 + (g - 64)] = (_Float16)(s * hx32[m * 64 + (g - 64)]);
            } else {
                float cnd = tanhf(v);
                float zz = (float)zbuf[m * 64 + g];
                outf[m * 64 + g] = (1.f - zz) * hx32[m * 64 + g] + zz * cnd;
            }
        }
    }
}

// ---------------- launch ----------------

extern "C" void kernel_launch(void* const* d_in, const int* in_sizes, int n_in,
                              void* d_out, int out_size, void* d_ws, size_t ws_size,
                              hipStream_t stream) {
    const float* inputs = (const float*)d_in[0];
    const float* hx     = (const float*)d_in[1];
    const int*   ei     = (const int*)d_in[2];
    const float* ew     = (const float*)d_in[3];
    const float* wg     = (const float*)d_in[4];
    const float* wc     = (const float*)d_in[5];
    const float* bg     = (const float*)d_in[6];
    const float* bc     = (const float*)d_in[7];
    float* out = (float*)d_out;

    // CSR + f16-weight footprint
    const size_t csr_bytes = (size_t)(NN + 1) * 4 + (size_t)NN * 4 * 2
                           + (size_t)EE_PAD * 6
                           + (size_t)(128 + 64) * FDIM * 2 + 512;
    // per-batch f16 intermediates: in_h,hx_h,rh,z (64 each) + W1h,W2h (128 each)
    const size_t per_batch = (size_t)NN * 512 * 2;   // 10.24 MB

    int bc_n = 1;
    const int cand[6] = {32, 16, 8, 4, 2, 1};
    for (int i = 0; i < 6; i++) {
        if (csr_bytes + (size_t)cand[i] * per_batch <= ws_size) { bc_n = cand[i]; break; }
    }

    // workspace layout (chunk-local, all f16 multiples of 16B)
    uint8_t* p = (uint8_t*)d_ws;
    _Float16* W1h  = (_Float16*)p; p += (size_t)bc_n * NN * 128 * 2;
    _Float16* W2h  = (_Float16*)p; p += (size_t)bc_n * NN * 128 * 2;
    _Float16* in_h = (_Float16*)p; p += (size_t)bc_n * NN * 64 * 2;
    _Float16* hx_h = (_Float16*)p; p += (size_t)bc_n * NN * 64 * 2;
    _Float16* rh   = (_Float16*)p; p += (size_t)bc_n * NN * 64 * 2;
    _Float16* zh   = (_Float16*)p; p += (size_t)bc_n * NN * 64 * 2;
    int* row_ptr = (int*)p;  p += (size_t)(NN + 1) * 4;
    p = (uint8_t*)(((uintptr_t)p + 15) & ~(uintptr_t)15);
    int* counts  = (int*)p;  p += (size_t)NN * 4;
    int* cursor  = (int*)p;  p += (size_t)NN * 4;            // counts,cursor,col,w contiguous
    int* col_s   = (int*)p;  p += (size_t)EE_PAD * 4;        // 16B-aligned (NN*8 mult of 16)
    _Float16* w_h = (_Float16*)p; p += (size_t)EE_PAD * 2;   // 8B-aligned accesses only
    p = (uint8_t*)(((uintptr_t)p + 63) & ~(uintptr_t)63);
    _Float16* whg = (_Float16*)p; p += (size_t)128 * FDIM * 2;
    _Float16* whc = (_Float16*)p;

    // CSR build (inputs re-restored every call -> rebuild every call).
    // One memset covers counts+cursor+col_s+w_h (pads must be col=0,w=0).
    hipMemsetAsync(counts, 0, (size_t)NN * 8 + (size_t)EE_PAD * 6, stream);
    count_kernel<<<(EE + 255) / 256, 256, 0, stream>>>(ei, counts);
    scan_kernel<<<1, 1024, 0, stream>>>(counts, row_ptr);
    fill_kernel<<<(EE + 255) / 256, 256, 0, stream>>>(ei, ew, row_ptr, cursor, col_s, w_h);
    wconv_kernel<<<(128 * FDIM + 255) / 256, 256, 0, stream>>>(wg, wc, whg, whc);

    for (int b0 = 0; b0 < BB; b0 += bc_n) {
        const float* in_c = inputs + (size_t)b0 * NN * 64;
        const float* hx_c = hx     + (size_t)b0 * NN * 64;
        float*       out_c = out   + (size_t)b0 * NN * 64;
        int Mchunk = bc_n * NN;
        int gemm_blocks = (Mchunk + 127) / 128;
        int n4 = bc_n * NN * 64 / 4;

        // f16 copies of this chunk's inputs/hx
        dim3 cg((n4 + 255) / 256, 2);
        cvt_h_kernel<<<cg, 256, 0, stream>>>(in_c, hx_c, in_h, hx_h, n4);

        int deltaA = (int)((const char*)hx_h - (const char*)in_h);

        // Pass A: x0 = [inputs|hx]  (both segments stride 64 f16 -> sh=7)
        spmm_full16<<<NB_FULL * bc_n, 256, 0, stream>>>(row_ptr, col_s, w_h,
                                                        in_h, 7, deltaA,
                                                        nullptr, nullptr, 1.f, W1h, bc_n);
        // W2 = 2*conv(W1) - x0  (W1 unified [row][128] -> sh=8, deltaB=128B)
        spmm_full16<<<NB_FULL * bc_n, 256, 0, stream>>>(row_ptr, col_s, w_h,
                                                        W1h, 8, 128,
                                                        in_h, hx_h, 2.f, W2h, bc_n);
        gemm_mfma<0><<<gemm_blocks, 512, 0, stream>>>(in_h, hx_h, W1h, W2h, whg, bg,
                                                      hx_c, nullptr, nullptr, zh, rh, Mchunk);
        // Pass B: x0' = [inputs|r*hx]; inputs-half of W1h/W2h reused from pass A
        spmm_half16<<<NB_HALF * bc_n, 256, 0, stream>>>(row_ptr, col_s, w_h, rh, 7,
                                                        nullptr, 1.f, W1h + 64, bc_n);
        spmm_half16<<<NB_HALF * bc_n, 256, 0, stream>>>(row_ptr, col_s, w_h, W1h + 64, 8,
                                                        rh, 2.f, W2h + 64, bc_n);
        gemm_mfma<1><<<gemm_blocks, 512, 0, stream>>>(in_h, rh, W1h, W2h, whc, bc,
                                                      hx_c, zh, out_c, nullptr, nullptr, Mchunk);
    }
}